// Round 12
// baseline (1607.865 us; speedup 1.0000x reference)
//
#include <hip/hip_runtime.h>
#include <hip/hip_bf16.h>
#include <math.h>

#define NPOS 81920   // 512*8*4*5
#define CDIM 256
#define SIGMA 1e-4f
#define LEAK 0.2f

typedef __hip_bfloat16 bf16;
typedef __bf16 bf16x8 __attribute__((ext_vector_type(8)));
typedef float f32x4 __attribute__((ext_vector_type(4)));

__device__ __forceinline__ float bf2f(unsigned short u) {
    return __uint_as_float(((unsigned)u) << 16);
}
__device__ __forceinline__ unsigned short f2bfu(float f) {
    bf16 h = __float2bfloat16(f);
    return *reinterpret_cast<unsigned short*>(&h);
}

// ---------------- encoder: h = tanh([x+sigma*noise, rand] @ W_enc) + pos_emb ----------------
__global__ void encode_kernel(const float* __restrict__ x, const float* __restrict__ noise,
                              const float* __restrict__ rnd, const float* __restrict__ We,
                              const float* __restrict__ pe, bf16* __restrict__ H) {
    int p = blockIdx.x;
    int c = threadIdx.x;
    float a = x[p] + SIGMA * noise[p];
    float b = rnd[p];
    float z = a * We[c] + b * We[CDIM + c];
    z = fminf(15.f, fmaxf(-15.f, z));
    float e = __expf(2.f * z);
    float th = 1.f - 2.f / (e + 1.f);   // tanh(z) via hw exp
    H[(size_t)p * CDIM + c] = __float2bfloat16(th + pe[(p % 160) * CDIM + c]);
}

// ---------------- bsum[l][c] = bo[l,0,c]+bo[l,1,c]+bo[l,2,c] ----------------
__global__ void bias3_kernel(const float* __restrict__ bo, float* __restrict__ bsum) {
    int l = blockIdx.x, c = threadIdx.x;
    bsum[l * CDIM + c] = bo[l * 768 + c] + bo[l * 768 + 256 + c] + bo[l * 768 + 512 + c];
}

// ---------------- weight packs ----------------
// WqkvT layout [l][a*768+n][k] (== [l][2304][256] B^T): n<256 -> Wq, else Wkv (k then v)
__global__ void pack_qkv_kernel(const float* __restrict__ Wq, const float* __restrict__ Wkv,
                                bf16* __restrict__ out) {
    int mat = blockIdx.x / 768;
    int n = blockIdx.x % 768;
    int k = threadIdx.x;
    float v = (n < 256) ? Wq[(size_t)mat * 65536 + (size_t)k * 256 + n]
                        : Wkv[(size_t)mat * 131072 + (size_t)k * 512 + (n - 256)];
    out[(size_t)blockIdx.x * 256 + k] = __float2bfloat16(v);
}
// WoT layout [l][n][a*256+ck] (== [l][256][768] B^T over stacked K): = Wo[l][a][ck][n]
__global__ void pack_wo_kernel(const float* __restrict__ Wo, bf16* __restrict__ out) {
    int l = blockIdx.x / 256;
    int n = blockIdx.x % 256;
    int ck = threadIdx.x;
    for (int a = 0; a < 3; a++)
        out[(size_t)(l * 256 + n) * 768 + a * 256 + ck] =
            __float2bfloat16(Wo[(((size_t)(l * 3 + a)) * 256 + ck) * 256 + n]);
}

// ================= step kernel: Wo GEMM (chunk t-1) + QKV GEMM (chunk t) ====================
// 48 KB static LDS -> 3 blocks/CU (was 64 KB -> 2). W blocks scheduled FIRST (long-K).
// G branch: C[mc x 2304] = A[mc x 256] @ Wqkv^T. 128x256 tile, BK=32, double-buffered
//   stage-after-barrier, swizzle slot = chunk ^ ((row>>1)&3) (verified 0 conflicts, r11).
// W branch: C[mc x 256] = O[mc x 768] @ WoT^T. 128x128 tile, BK=32 (32 KB), 24 iters,
//   epilogue adds bias + leaky-relu.
__global__ __launch_bounds__(256, 3) void step_kernel(
    const bf16* __restrict__ Hg, const bf16* __restrict__ Wqkv, bf16* __restrict__ QKV,
    const bf16* __restrict__ O, const bf16* __restrict__ WoTl, bf16* __restrict__ Hnw,
    const float* __restrict__ bias, int nW, int nMblk) {
    __shared__ __bf16 smem[24576];  // 48 KB
    int tid = threadIdx.x;
    int wave = tid >> 6, lane = tid & 63;
    int quad = lane >> 4, m = lane & 15;

    if (blockIdx.x >= nW) {
        // ---------------- G: QKV projection, 128x256 tile, BK=32, K=256 ----------------
        __bf16* As = smem;              // [2][128*32]  (2 x 8 KB)
        __bf16* Bs = smem + 8192;       // [2][256*32]  (2 x 16 KB)
        int bid = blockIdx.x - nW;
        int xcd = bid & 7, slot = bid >> 3;
        int g = slot / 9;
        int nb = slot - g * 9;          // 9 N-blocks of 256
        int mb = xcd + 8 * g;           // nMblk multiple of 8 (mc mult of 1024)
        int bm = mb * 128, bn = nb * 256;
        int wr = (wave >> 1) * 64, wc = (wave & 1) * 128;
        f32x4 acc[4][8] = {};

#define STAGE_G(buf, k0)                                                                       \
    {                                                                                          \
        _Pragma("unroll") for (int rep = 0; rep < 2; rep++) {                                  \
            int ch = rep * 256 + wave * 64 + lane;                                             \
            int row = ch >> 2, cc = ch & 3, gc = cc ^ ((row >> 1) & 3);                        \
            __builtin_amdgcn_global_load_lds(                                                  \
                (const __attribute__((address_space(1))) void*)(Hg + (size_t)(bm + row) * CDIM \
                                                                + (k0) + gc * 8),              \
                (__attribute__((address_space(3))) void*)(As + (buf) * 4096                    \
                                                          + (rep * 256 + wave * 64) * 8),      \
                16, 0, 0);                                                                     \
        }                                                                                      \
        _Pragma("unroll") for (int rep = 0; rep < 4; rep++) {                                  \
            int ch = rep * 256 + wave * 64 + lane;                                             \
            int row = ch >> 2, cc = ch & 3, gc = cc ^ ((row >> 1) & 3);                        \
            __builtin_amdgcn_global_load_lds(                                                  \
                (const __attribute__((address_space(1))) void*)(Wqkv + (size_t)(bn + row) * 256\
                                                                + (k0) + gc * 8),              \
                (__attribute__((address_space(3))) void*)(Bs + (buf) * 8192                    \
                                                          + (rep * 256 + wave * 64) * 8),      \
                16, 0, 0);                                                                     \
        }                                                                                      \
    }

        STAGE_G(0, 0);
#pragma unroll
        for (int it = 0; it < 8; it++) {
            __syncthreads();
            if (it < 7) STAGE_G((it + 1) & 1, (it + 1) * 32);
            const __bf16* Ab = As + (it & 1) * 4096;
            const __bf16* Bb = Bs + (it & 1) * 8192;
            bf16x8 af[4], bfr[8];
#pragma unroll
            for (int i = 0; i < 4; i++) {
                int r = wr + i * 16 + m;
                af[i] = *(const bf16x8*)(Ab + r * 32 + ((quad ^ ((r >> 1) & 3)) * 8));
            }
#pragma unroll
            for (int j = 0; j < 8; j++) {
                int r = wc + j * 16 + m;
                bfr[j] = *(const bf16x8*)(Bb + r * 32 + ((quad ^ ((r >> 1) & 3)) * 8));
            }
#pragma unroll
            for (int i = 0; i < 4; i++)
#pragma unroll
                for (int j = 0; j < 8; j++)
                    acc[i][j] = __builtin_amdgcn_mfma_f32_16x16x32_bf16(af[i], bfr[j], acc[i][j], 0, 0, 0);
        }
#undef STAGE_G

#pragma unroll
        for (int i = 0; i < 4; i++)
#pragma unroll
            for (int j = 0; j < 8; j++)
#pragma unroll
                for (int r = 0; r < 4; r++) {
                    int row = bm + wr + i * 16 + quad * 4 + r;
                    int col = bn + wc + j * 16 + m;
                    QKV[(size_t)row * 2304 + col] = __float2bfloat16(acc[i][j][r]);
                }
    } else {
        // ---------------- W: Wo projection, 128x128 tile, BK=32, K=768 ----------------
        __bf16* As = smem;              // [2][128*32]  (2 x 8 KB)
        __bf16* Bs = smem + 8192;       // [2][128*32]
        int bid = blockIdx.x;
        int xcd = bid & 7, slot = bid >> 3;
        int g = slot >> 1;
        int nb = slot & 1;              // 2 N-blocks of 128
        int mb = xcd + 8 * g;
        int bm = mb * 128, bn = nb * 128;
        int wr = (wave >> 1) * 64, wc = (wave & 1) * 64;
        f32x4 acc[4][4] = {};

#define STAGE_W(buf, k0)                                                                       \
    {                                                                                          \
        _Pragma("unroll") for (int rep = 0; rep < 2; rep++) {                                  \
            int ch = rep * 256 + wave * 64 + lane;                                             \
            int row = ch >> 2, cc = ch & 3, gc = cc ^ ((row >> 1) & 3);                        \
            __builtin_amdgcn_global_load_lds(                                                  \
                (const __attribute__((address_space(1))) void*)(O + (size_t)(bm + row) * 768   \
                                                                + (k0) + gc * 8),              \
                (__attribute__((address_space(3))) void*)(As + (buf) * 4096                    \
                                                          + (rep * 256 + wave * 64) * 8),      \
                16, 0, 0);                                                                     \
        }                                                                                      \
        _Pragma("unroll") for (int rep = 0; rep < 2; rep++) {                                  \
            int ch = rep * 256 + wave * 64 + lane;                                             \
            int row = ch >> 2, cc = ch & 3, gc = cc ^ ((row >> 1) & 3);                        \
            __builtin_amdgcn_global_load_lds(                                                  \
                (const __attribute__((address_space(1))) void*)(WoTl + (size_t)(bn + row) * 768\
                                                                + (k0) + gc * 8),              \
                (__attribute__((address_space(3))) void*)(Bs + (buf) * 4096                    \
                                                          + (rep * 256 + wave * 64) * 8),      \
                16, 0, 0);                                                                     \
        }                                                                                      \
    }

        STAGE_W(0, 0);
#pragma unroll
        for (int it = 0; it < 24; it++) {
            __syncthreads();
            if (it < 23) STAGE_W((it + 1) & 1, (it + 1) * 32);
            const __bf16* Ab = As + (it & 1) * 4096;
            const __bf16* Bb = Bs + (it & 1) * 4096;
            bf16x8 af[4], bfr[4];
#pragma unroll
            for (int i = 0; i < 4; i++) {
                int r = wr + i * 16 + m;
                af[i] = *(const bf16x8*)(Ab + r * 32 + ((quad ^ ((r >> 1) & 3)) * 8));
            }
#pragma unroll
            for (int j = 0; j < 4; j++) {
                int r = wc + j * 16 + m;
                bfr[j] = *(const bf16x8*)(Bb + r * 32 + ((quad ^ ((r >> 1) & 3)) * 8));
            }
#pragma unroll
            for (int i = 0; i < 4; i++)
#pragma unroll
                for (int j = 0; j < 4; j++)
                    acc[i][j] = __builtin_amdgcn_mfma_f32_16x16x32_bf16(af[i], bfr[j], acc[i][j], 0, 0, 0);
        }
#undef STAGE_W

#pragma unroll
        for (int i = 0; i < 4; i++)
#pragma unroll
            for (int j = 0; j < 4; j++)
#pragma unroll
                for (int r = 0; r < 4; r++) {
                    int row = bm + wr + i * 16 + quad * 4 + r;
                    int col = bn + wc + j * 16 + m;
                    float v = acc[i][j][r] + bias[col];
                    v = v >= 0.f ? v : LEAK * v;
                    Hnw[(size_t)row * CDIM + col] = __float2bfloat16(v);
                }
    }
}

// ---------------- fused axial attention: all 3 axes, one dispatch (0 LDS, high occ) ---------
// QKV row = 2304 bf16 (= 3 x [q|k|v]); output -> O row = 768 bf16 (= [o0|o1|o2]).
template <int AXIS>
__device__ __forceinline__ void attn_axis(const bf16* __restrict__ QKV, bf16* __restrict__ O,
                                          int seq, int lane) {
    constexpr int T      = (AXIS == 0) ? 8 : (AXIS == 1) ? 4 : 5;
    constexpr int STRIDE = (AXIS == 0) ? 20 : (AXIS == 1) ? 5 : 1;
    int base;
    if (AXIS == 0)      { int b = seq / 20, r = seq % 20; base = b * 160 + r; }
    else if (AXIS == 1) { int b = seq / 40, r = seq % 40; base = b * 160 + (r / 5) * 20 + (r % 5); }
    else                { int b = seq / 32, r = seq % 32; base = b * 160 + r * 5; }

    float q[T][4], k[T][4], v[T][4];
#pragma unroll
    for (int t = 0; t < T; t++) {
        const unsigned short* rowp =
            (const unsigned short*)QKV + (size_t)(base + t * STRIDE) * 2304 + AXIS * 768 + lane * 4;
        ushort4 qu = *(const ushort4*)(rowp);
        ushort4 ku = *(const ushort4*)(rowp + 256);
        ushort4 vu = *(const ushort4*)(rowp + 512);
        q[t][0] = bf2f(qu.x); q[t][1] = bf2f(qu.y); q[t][2] = bf2f(qu.z); q[t][3] = bf2f(qu.w);
        k[t][0] = bf2f(ku.x); k[t][1] = bf2f(ku.y); k[t][2] = bf2f(ku.z); k[t][3] = bf2f(ku.w);
        v[t][0] = bf2f(vu.x); v[t][1] = bf2f(vu.y); v[t][2] = bf2f(vu.z); v[t][3] = bf2f(vu.w);
    }

#pragma unroll
    for (int t = 0; t < T; t++) {
        float sc[T];
#pragma unroll
        for (int s = 0; s < T; s++) {
            float p = q[t][0] * k[s][0] + q[t][1] * k[s][1] + q[t][2] * k[s][2] + q[t][3] * k[s][3];
            p += __shfl_xor(p, 1);
            p += __shfl_xor(p, 2);
            sc[s] = p * 0.25f;  // * DH^-0.5
        }
        float mx = sc[0];
#pragma unroll
        for (int s = 1; s < T; s++) mx = fmaxf(mx, sc[s]);
        float sum = 0.f;
#pragma unroll
        for (int s = 0; s < T; s++) { sc[s] = __expf(sc[s] - mx); sum += sc[s]; }
        float inv = 1.f / sum;
        float o0 = 0.f, o1 = 0.f, o2 = 0.f, o3 = 0.f;
#pragma unroll
        for (int s = 0; s < T; s++) {
            o0 += sc[s] * v[s][0]; o1 += sc[s] * v[s][1];
            o2 += sc[s] * v[s][2]; o3 += sc[s] * v[s][3];
        }
        ushort4 st;
        st.x = f2bfu(o0 * inv); st.y = f2bfu(o1 * inv);
        st.z = f2bfu(o2 * inv); st.w = f2bfu(o3 * inv);
        *(ushort4*)((unsigned short*)O + (size_t)(base + t * STRIDE) * 768 + AXIS * 256 + lane * 4) = st;
    }
}

__global__ __launch_bounds__(256) void attn_all(const bf16* __restrict__ QKV,
                                                bf16* __restrict__ O, int n0, int n1) {
    int wave = threadIdx.x >> 6, lane = threadIdx.x & 63;
    int blk = blockIdx.x;
    if (blk < n0)            attn_axis<0>(QKV, O, blk * 4 + wave, lane);
    else if (blk < n0 + n1)  attn_axis<1>(QKV, O, (blk - n0) * 4 + wave, lane);
    else                     attn_axis<2>(QKV, O, (blk - n0 - n1) * 4 + wave, lane);
}

// ---------------- decoder: out = sigmoid(H @ Wd + bd) ----------------
__global__ void decode_kernel(const bf16* __restrict__ H, const float* __restrict__ Wd,
                              const float* __restrict__ bd, float* __restrict__ out) {
    int tid = threadIdx.x;
    int pos = blockIdx.x * 4 + (tid >> 6);
    int lane = tid & 63;
    float acc = 0.f;
#pragma unroll
    for (int q = 0; q < 4; q++) {
        int c = lane + q * 64;
        acc += __bfloat162float(H[(size_t)pos * CDIM + c]) * Wd[c];
    }
#pragma unroll
    for (int off = 32; off > 0; off >>= 1) acc += __shfl_down(acc, off);
    if (lane == 0) out[pos] = 1.f / (1.f + __expf(-(acc + bd[0])));
}

extern "C" void kernel_launch(void* const* d_in, const int* in_sizes, int n_in,
                              void* d_out, int out_size, void* d_ws, size_t ws_size,
                              hipStream_t stream) {
    const float* x     = (const float*)d_in[0];
    const float* noise = (const float*)d_in[1];
    const float* rnd   = (const float*)d_in[2];
    const float* We    = (const float*)d_in[3];
    const float* pe    = (const float*)d_in[4];
    const float* Wq    = (const float*)d_in[5];
    const float* Wkv   = (const float*)d_in[6];
    const float* Wo    = (const float*)d_in[7];
    const float* bo    = (const float*)d_in[8];
    const float* Wd    = (const float*)d_in[9];
    const float* bd    = (const float*)d_in[10];
    float* out = (float*)d_out;

    // ws: H0 | H1 | WqkvT | WoT | bsum | QKV (single) | O (single)  (c=4 -> ~215 MB)
    bf16* H0    = (bf16*)d_ws;
    bf16* H1    = H0 + (size_t)NPOS * CDIM;
    bf16* WqkvT = H1 + (size_t)NPOS * CDIM;
    bf16* WoT   = WqkvT + (size_t)2 * 2304 * 256;
    float* bsum = (float*)(WoT + (size_t)2 * 256 * 768);
    bf16* QKV   = (bf16*)(bsum + 512);

    size_t fixed = ((size_t)2 * NPOS * CDIM + (size_t)2 * 2304 * 256 + (size_t)2 * 256 * 768) * 2
                   + 512 * 4;
    int c = 4;  // mc = 20480: multiple of 1024 (XCD swizzle) and 160 (attn)
    while (c < 64 && fixed + (size_t)(NPOS / c) * (2304 + 768) * 2 > ws_size) c <<= 1;
    int mc = NPOS / c;
    bf16* O = QKV + (size_t)mc * 2304;
    bf16* Hbuf[3] = { H0, H1, H0 };  // layer l: reads Hbuf[l], W writes Hbuf[l+1]

    pack_qkv_kernel<<<6 * 768, 256, 0, stream>>>(Wq, Wkv, WqkvT);
    pack_wo_kernel<<<2 * 256, 256, 0, stream>>>(Wo, WoT);
    bias3_kernel<<<2, 256, 0, stream>>>(bo, bsum);
    encode_kernel<<<NPOS, 256, 0, stream>>>(x, noise, rnd, We, pe, H0);

    int nMblk = mc / 128;
    int n0 = (mc / 160) * 20 / 4, n1 = (mc / 160) * 40 / 4, n2 = (mc / 160) * 32 / 4;
    int TT = 2 * c;

    for (int t = 0; t <= TT; t++) {
        int gG = (t < TT) ? nMblk * 9 : 0;   // QKV: 9 N-blocks of 256
        int gW = (t >= 1) ? nMblk * 2 : 0;   // Wo: 2 N-blocks of 128 (scheduled first)
        const bf16 *Hg = nullptr, *Wq_ = nullptr;
        if (gG) {
            int lg = t / c, cg = t % c;
            Hg = Hbuf[lg] + (size_t)cg * mc * CDIM;
            Wq_ = WqkvT + (size_t)lg * 2304 * 256;
        }
        const bf16* WoTl = nullptr; bf16* Hnw = nullptr; const float* bs = nullptr;
        if (gW) {
            int tw = t - 1, lw = tw / c, cw = tw % c;
            WoTl = WoT + (size_t)lw * 256 * 768;
            Hnw = Hbuf[lw + 1] + (size_t)cw * mc * CDIM;
            bs = bsum + lw * CDIM;
        }
        step_kernel<<<gG + gW, 256, 0, stream>>>(Hg, Wq_, QKV, O, WoTl, Hnw, bs, gW, nMblk);
        if (t < TT) attn_all<<<n0 + n1 + n2, 256, 0, stream>>>(QKV, O, n0, n1);
    }

    decode_kernel<<<NPOS / 4, 256, 0, stream>>>(Hbuf[2], Wd, bd, out);
}

// Round 13
// 674.803 us; speedup vs baseline: 2.3827x; 2.3827x over previous
//
#include <hip/hip_runtime.h>
#include <hip/hip_bf16.h>
#include <math.h>

#define NPOS 81920   // 512*8*4*5
#define CDIM 256
#define SIGMA 1e-4f
#define LEAK 0.2f

typedef __hip_bfloat16 bf16;
typedef __bf16 bf16x8 __attribute__((ext_vector_type(8)));
typedef float f32x4 __attribute__((ext_vector_type(4)));

__device__ __forceinline__ float bf2f(unsigned short u) {
    return __uint_as_float(((unsigned)u) << 16);
}
__device__ __forceinline__ unsigned short f2bfu(float f) {
    bf16 h = __float2bfloat16(f);
    return *reinterpret_cast<unsigned short*>(&h);
}

// ---------------- encoder: h = tanh([x+sigma*noise, rand] @ W_enc) + pos_emb ----------------
__global__ void encode_kernel(const float* __restrict__ x, const float* __restrict__ noise,
                              const float* __restrict__ rnd, const float* __restrict__ We,
                              const float* __restrict__ pe, bf16* __restrict__ H) {
    int p = blockIdx.x;
    int c = threadIdx.x;
    float a = x[p] + SIGMA * noise[p];
    float b = rnd[p];
    float z = a * We[c] + b * We[CDIM + c];
    z = fminf(15.f, fmaxf(-15.f, z));
    float e = __expf(2.f * z);
    float th = 1.f - 2.f / (e + 1.f);   // tanh(z) via hw exp
    H[(size_t)p * CDIM + c] = __float2bfloat16(th + pe[(p % 160) * CDIM + c]);
}

// ---------------- bsum[l][c] = bo[l,0,c]+bo[l,1,c]+bo[l,2,c] ----------------
__global__ void bias3_kernel(const float* __restrict__ bo, float* __restrict__ bsum) {
    int l = blockIdx.x, c = threadIdx.x;
    bsum[l * CDIM + c] = bo[l * 768 + c] + bo[l * 768 + 256 + c] + bo[l * 768 + 512 + c];
}

// ---------------- weight packs ----------------
// WqkvT layout [l][a*768+n][k] (== [l][2304][256] B^T): n<256 -> Wq, else Wkv (k then v)
__global__ void pack_qkv_kernel(const float* __restrict__ Wq, const float* __restrict__ Wkv,
                                bf16* __restrict__ out) {
    int mat = blockIdx.x / 768;
    int n = blockIdx.x % 768;
    int k = threadIdx.x;
    float v = (n < 256) ? Wq[(size_t)mat * 65536 + (size_t)k * 256 + n]
                        : Wkv[(size_t)mat * 131072 + (size_t)k * 512 + (n - 256)];
    out[(size_t)blockIdx.x * 256 + k] = __float2bfloat16(v);
}
// WoT layout [l][n][a*256+ck] (== [l][256][768] B^T over stacked K): = Wo[l][a][ck][n]
__global__ void pack_wo_kernel(const float* __restrict__ Wo, bf16* __restrict__ out) {
    int l = blockIdx.x / 256;
    int n = blockIdx.x % 256;
    int ck = threadIdx.x;
    for (int a = 0; a < 3; a++)
        out[(size_t)(l * 256 + n) * 768 + a * 256 + ck] =
            __float2bfloat16(Wo[(((size_t)(l * 3 + a)) * 256 + ck) * 256 + n]);
}

// ================= step kernel: Wo GEMM (chunk t-1, FIRST) + QKV GEMM (chunk t) =============
// round-11 engine (best known: 51 us/step, 0 conflicts, no spill). 64 KB LDS, 2 blocks/CU.
// NOTE (r12 post-mortem): the 128x256 G tile needs ~248 unified VGPR+AGPR regs/wave ->
// pinned at 2 blocks/CU; forcing 3 via __launch_bounds__ spills accumulators (170->488 MB
// scratch traffic, 2.3x slower). Do NOT cap registers tighter than (256,2).
// G branch: C[mc x 2304] = A[mc x 256] @ Wqkv^T. 128x256 tile, BK=32, double-buffered
//   stage-after-barrier, swizzle slot = chunk ^ ((row>>1)&3) (verified 0 conflicts, r11).
// W branch: C[mc x 256] = O[mc x 768] @ WoT^T. 128x128 tile, BK=64, 12 pipelined iters,
//   epilogue adds bias + leaky-relu. W blocks first: longest-K blocks launch earliest.
__global__ __launch_bounds__(256, 2) void step_kernel(
    const bf16* __restrict__ Hg, const bf16* __restrict__ Wqkv, bf16* __restrict__ QKV,
    const bf16* __restrict__ O, const bf16* __restrict__ WoTl, bf16* __restrict__ Hnw,
    const float* __restrict__ bias, int nW, int nMblk) {
    __shared__ __bf16 smem[32768];  // 64 KB; G uses 48 KB of it, W uses all 64
    int tid = threadIdx.x;
    int wave = tid >> 6, lane = tid & 63;
    int quad = lane >> 4, m = lane & 15;

    if (blockIdx.x >= nW) {
        // ---------------- G: QKV projection, 128x256 tile, BK=32, K=256 ----------------
        __bf16* As = smem;              // [2][128*32]  (2 x 8 KB)
        __bf16* Bs = smem + 8192;       // [2][256*32]  (2 x 16 KB)
        int bid = blockIdx.x - nW;
        int xcd = bid & 7, slot = bid >> 3;
        int g = slot / 9;
        int nb = slot - g * 9;          // 9 N-blocks of 256
        int mb = xcd + 8 * g;           // nMblk multiple of 8 (mc mult of 1024)
        int bm = mb * 128, bn = nb * 256;
        int wr = (wave >> 1) * 64, wc = (wave & 1) * 128;
        f32x4 acc[4][8] = {};

#define STAGE_G(buf, k0)                                                                       \
    {                                                                                          \
        _Pragma("unroll") for (int rep = 0; rep < 2; rep++) {                                  \
            int ch = rep * 256 + wave * 64 + lane;                                             \
            int row = ch >> 2, cc = ch & 3, gc = cc ^ ((row >> 1) & 3);                        \
            __builtin_amdgcn_global_load_lds(                                                  \
                (const __attribute__((address_space(1))) void*)(Hg + (size_t)(bm + row) * CDIM \
                                                                + (k0) + gc * 8),              \
                (__attribute__((address_space(3))) void*)(As + (buf) * 4096                    \
                                                          + (rep * 256 + wave * 64) * 8),      \
                16, 0, 0);                                                                     \
        }                                                                                      \
        _Pragma("unroll") for (int rep = 0; rep < 4; rep++) {                                  \
            int ch = rep * 256 + wave * 64 + lane;                                             \
            int row = ch >> 2, cc = ch & 3, gc = cc ^ ((row >> 1) & 3);                        \
            __builtin_amdgcn_global_load_lds(                                                  \
                (const __attribute__((address_space(1))) void*)(Wqkv + (size_t)(bn + row) * 256\
                                                                + (k0) + gc * 8),              \
                (__attribute__((address_space(3))) void*)(Bs + (buf) * 8192                    \
                                                          + (rep * 256 + wave * 64) * 8),      \
                16, 0, 0);                                                                     \
        }                                                                                      \
    }

        STAGE_G(0, 0);
#pragma unroll
        for (int it = 0; it < 8; it++) {
            __syncthreads();
            if (it < 7) STAGE_G((it + 1) & 1, (it + 1) * 32);
            const __bf16* Ab = As + (it & 1) * 4096;
            const __bf16* Bb = Bs + (it & 1) * 8192;
            bf16x8 af[4], bfr[8];
#pragma unroll
            for (int i = 0; i < 4; i++) {
                int r = wr + i * 16 + m;
                af[i] = *(const bf16x8*)(Ab + r * 32 + ((quad ^ ((r >> 1) & 3)) * 8));
            }
#pragma unroll
            for (int j = 0; j < 8; j++) {
                int r = wc + j * 16 + m;
                bfr[j] = *(const bf16x8*)(Bb + r * 32 + ((quad ^ ((r >> 1) & 3)) * 8));
            }
#pragma unroll
            for (int i = 0; i < 4; i++)
#pragma unroll
                for (int j = 0; j < 8; j++)
                    acc[i][j] = __builtin_amdgcn_mfma_f32_16x16x32_bf16(af[i], bfr[j], acc[i][j], 0, 0, 0);
        }
#undef STAGE_G

#pragma unroll
        for (int i = 0; i < 4; i++)
#pragma unroll
            for (int j = 0; j < 8; j++)
#pragma unroll
                for (int r = 0; r < 4; r++) {
                    int row = bm + wr + i * 16 + quad * 4 + r;
                    int col = bn + wc + j * 16 + m;
                    QKV[(size_t)row * 2304 + col] = __float2bfloat16(acc[i][j][r]);
                }
    } else {
        // ---------------- W: Wo projection, 128x128 tile, BK=64, K=768 ----------------
        __bf16* As = smem;              // [2][128*64]  (2 x 16 KB)
        __bf16* Bs = smem + 16384;      // [2][128*64]
        int bid = blockIdx.x;
        int xcd = bid & 7, slot = bid >> 3;
        int g = slot >> 1;
        int nb = slot & 1;              // 2 N-blocks of 128
        int mb = xcd + 8 * g;
        int bm = mb * 128, bn = nb * 128;
        int wr = (wave >> 1) * 64, wc = (wave & 1) * 64;
        f32x4 acc[4][4] = {};

#define STAGE_W(buf, k0)                                                                       \
    {                                                                                          \
        _Pragma("unroll") for (int rep = 0; rep < 4; rep++) {                                  \
            int ch = rep * 256 + wave * 64 + lane;                                             \
            int row = ch >> 3, cc = ch & 7, gc = cc ^ (row & 7);                               \
            __builtin_amdgcn_global_load_lds(                                                  \
                (const __attribute__((address_space(1))) void*)(O + (size_t)(bm + row) * 768   \
                                                                + (k0) + gc * 8),              \
                (__attribute__((address_space(3))) void*)(As + (buf) * 8192                    \
                                                          + (rep * 256 + wave * 64) * 8),      \
                16, 0, 0);                                                                     \
        }                                                                                      \
        _Pragma("unroll") for (int rep = 0; rep < 4; rep++) {                                  \
            int ch = rep * 256 + wave * 64 + lane;                                             \
            int row = ch >> 3, cc = ch & 7, gc = cc ^ (row & 7);                               \
            __builtin_amdgcn_global_load_lds(                                                  \
                (const __attribute__((address_space(1))) void*)(WoTl + (size_t)(bn + row) * 768\
                                                                + (k0) + gc * 8),              \
                (__attribute__((address_space(3))) void*)(Bs + (buf) * 8192                    \
                                                          + (rep * 256 + wave * 64) * 8),      \
                16, 0, 0);                                                                     \
        }                                                                                      \
    }

        STAGE_W(0, 0);
#pragma unroll
        for (int it = 0; it < 12; it++) {
            __syncthreads();
            if (it < 11) STAGE_W((it + 1) & 1, (it + 1) * 64);
            const __bf16* Ab = As + (it & 1) * 8192;
            const __bf16* Bb = Bs + (it & 1) * 8192;
#pragma unroll
            for (int kk = 0; kk < 2; kk++) {
                bf16x8 af[4], bfr[4];
#pragma unroll
                for (int i = 0; i < 4; i++) {
                    int r = wr + i * 16 + m, cix = kk * 4 + quad;
                    af[i] = *(const bf16x8*)(Ab + r * 64 + ((cix ^ (r & 7)) * 8));
                }
#pragma unroll
                for (int j = 0; j < 4; j++) {
                    int r = wc + j * 16 + m, cix = kk * 4 + quad;
                    bfr[j] = *(const bf16x8*)(Bb + r * 64 + ((cix ^ (r & 7)) * 8));
                }
#pragma unroll
                for (int i = 0; i < 4; i++)
#pragma unroll
                    for (int j = 0; j < 4; j++)
                        acc[i][j] = __builtin_amdgcn_mfma_f32_16x16x32_bf16(af[i], bfr[j], acc[i][j], 0, 0, 0);
            }
        }
#undef STAGE_W

#pragma unroll
        for (int i = 0; i < 4; i++)
#pragma unroll
            for (int j = 0; j < 4; j++)
#pragma unroll
                for (int r = 0; r < 4; r++) {
                    int row = bm + wr + i * 16 + quad * 4 + r;
                    int col = bn + wc + j * 16 + m;
                    float v = acc[i][j][r] + bias[col];
                    v = v >= 0.f ? v : LEAK * v;
                    Hnw[(size_t)row * CDIM + col] = __float2bfloat16(v);
                }
    }
}

// ---------------- fused axial attention: all 3 axes, one dispatch (0 LDS, high occ) ---------
// QKV row = 2304 bf16 (= 3 x [q|k|v]); output -> O row = 768 bf16 (= [o0|o1|o2]).
template <int AXIS>
__device__ __forceinline__ void attn_axis(const bf16* __restrict__ QKV, bf16* __restrict__ O,
                                          int seq, int lane) {
    constexpr int T      = (AXIS == 0) ? 8 : (AXIS == 1) ? 4 : 5;
    constexpr int STRIDE = (AXIS == 0) ? 20 : (AXIS == 1) ? 5 : 1;
    int base;
    if (AXIS == 0)      { int b = seq / 20, r = seq % 20; base = b * 160 + r; }
    else if (AXIS == 1) { int b = seq / 40, r = seq % 40; base = b * 160 + (r / 5) * 20 + (r % 5); }
    else                { int b = seq / 32, r = seq % 32; base = b * 160 + r * 5; }

    float q[T][4], k[T][4], v[T][4];
#pragma unroll
    for (int t = 0; t < T; t++) {
        const unsigned short* rowp =
            (const unsigned short*)QKV + (size_t)(base + t * STRIDE) * 2304 + AXIS * 768 + lane * 4;
        ushort4 qu = *(const ushort4*)(rowp);
        ushort4 ku = *(const ushort4*)(rowp + 256);
        ushort4 vu = *(const ushort4*)(rowp + 512);
        q[t][0] = bf2f(qu.x); q[t][1] = bf2f(qu.y); q[t][2] = bf2f(qu.z); q[t][3] = bf2f(qu.w);
        k[t][0] = bf2f(ku.x); k[t][1] = bf2f(ku.y); k[t][2] = bf2f(ku.z); k[t][3] = bf2f(ku.w);
        v[t][0] = bf2f(vu.x); v[t][1] = bf2f(vu.y); v[t][2] = bf2f(vu.z); v[t][3] = bf2f(vu.w);
    }

#pragma unroll
    for (int t = 0; t < T; t++) {
        float sc[T];
#pragma unroll
        for (int s = 0; s < T; s++) {
            float p = q[t][0] * k[s][0] + q[t][1] * k[s][1] + q[t][2] * k[s][2] + q[t][3] * k[s][3];
            p += __shfl_xor(p, 1);
            p += __shfl_xor(p, 2);
            sc[s] = p * 0.25f;  // * DH^-0.5
        }
        float mx = sc[0];
#pragma unroll
        for (int s = 1; s < T; s++) mx = fmaxf(mx, sc[s]);
        float sum = 0.f;
#pragma unroll
        for (int s = 0; s < T; s++) { sc[s] = __expf(sc[s] - mx); sum += sc[s]; }
        float inv = 1.f / sum;
        float o0 = 0.f, o1 = 0.f, o2 = 0.f, o3 = 0.f;
#pragma unroll
        for (int s = 0; s < T; s++) {
            o0 += sc[s] * v[s][0]; o1 += sc[s] * v[s][1];
            o2 += sc[s] * v[s][2]; o3 += sc[s] * v[s][3];
        }
        ushort4 st;
        st.x = f2bfu(o0 * inv); st.y = f2bfu(o1 * inv);
        st.z = f2bfu(o2 * inv); st.w = f2bfu(o3 * inv);
        *(ushort4*)((unsigned short*)O + (size_t)(base + t * STRIDE) * 768 + AXIS * 256 + lane * 4) = st;
    }
}

__global__ __launch_bounds__(256) void attn_all(const bf16* __restrict__ QKV,
                                                bf16* __restrict__ O, int n0, int n1) {
    int wave = threadIdx.x >> 6, lane = threadIdx.x & 63;
    int blk = blockIdx.x;
    if (blk < n0)            attn_axis<0>(QKV, O, blk * 4 + wave, lane);
    else if (blk < n0 + n1)  attn_axis<1>(QKV, O, (blk - n0) * 4 + wave, lane);
    else                     attn_axis<2>(QKV, O, (blk - n0 - n1) * 4 + wave, lane);
}

// ---------------- decoder: out = sigmoid(H @ Wd + bd) ----------------
__global__ void decode_kernel(const bf16* __restrict__ H, const float* __restrict__ Wd,
                              const float* __restrict__ bd, float* __restrict__ out) {
    int tid = threadIdx.x;
    int pos = blockIdx.x * 4 + (tid >> 6);
    int lane = tid & 63;
    float acc = 0.f;
#pragma unroll
    for (int q = 0; q < 4; q++) {
        int c = lane + q * 64;
        acc += __bfloat162float(H[(size_t)pos * CDIM + c]) * Wd[c];
    }
#pragma unroll
    for (int off = 32; off > 0; off >>= 1) acc += __shfl_down(acc, off);
    if (lane == 0) out[pos] = 1.f / (1.f + __expf(-(acc + bd[0])));
}

extern "C" void kernel_launch(void* const* d_in, const int* in_sizes, int n_in,
                              void* d_out, int out_size, void* d_ws, size_t ws_size,
                              hipStream_t stream) {
    const float* x     = (const float*)d_in[0];
    const float* noise = (const float*)d_in[1];
    const float* rnd   = (const float*)d_in[2];
    const float* We    = (const float*)d_in[3];
    const float* pe    = (const float*)d_in[4];
    const float* Wq    = (const float*)d_in[5];
    const float* Wkv   = (const float*)d_in[6];
    const float* Wo    = (const float*)d_in[7];
    const float* bo    = (const float*)d_in[8];
    const float* Wd    = (const float*)d_in[9];
    const float* bd    = (const float*)d_in[10];
    float* out = (float*)d_out;

    // ws: H0 | H1 | WqkvT | WoT | bsum | QKV (single) | O (single)  (c=4 -> ~215 MB)
    bf16* H0    = (bf16*)d_ws;
    bf16* H1    = H0 + (size_t)NPOS * CDIM;
    bf16* WqkvT = H1 + (size_t)NPOS * CDIM;
    bf16* WoT   = WqkvT + (size_t)2 * 2304 * 256;
    float* bsum = (float*)(WoT + (size_t)2 * 256 * 768);
    bf16* QKV   = (bf16*)(bsum + 512);

    size_t fixed = ((size_t)2 * NPOS * CDIM + (size_t)2 * 2304 * 256 + (size_t)2 * 256 * 768) * 2
                   + 512 * 4;
    int c = 4;  // mc = 20480: multiple of 1024 (XCD swizzle) and 160 (attn)
    while (c < 64 && fixed + (size_t)(NPOS / c) * (2304 + 768) * 2 > ws_size) c <<= 1;
    int mc = NPOS / c;
    bf16* O = QKV + (size_t)mc * 2304;
    bf16* Hbuf[3] = { H0, H1, H0 };  // layer l: reads Hbuf[l], W writes Hbuf[l+1]

    pack_qkv_kernel<<<6 * 768, 256, 0, stream>>>(Wq, Wkv, WqkvT);
    pack_wo_kernel<<<2 * 256, 256, 0, stream>>>(Wo, WoT);
    bias3_kernel<<<2, 256, 0, stream>>>(bo, bsum);
    encode_kernel<<<NPOS, 256, 0, stream>>>(x, noise, rnd, We, pe, H0);

    int nMblk = mc / 128;
    int n0 = (mc / 160) * 20 / 4, n1 = (mc / 160) * 40 / 4, n2 = (mc / 160) * 32 / 4;
    int TT = 2 * c;

    for (int t = 0; t <= TT; t++) {
        int gG = (t < TT) ? nMblk * 9 : 0;   // QKV: 9 N-blocks of 256
        int gW = (t >= 1) ? nMblk * 2 : 0;   // Wo: 2 N-blocks of 128 (scheduled first)
        const bf16 *Hg = nullptr, *Wq_ = nullptr;
        if (gG) {
            int lg = t / c, cg = t % c;
            Hg = Hbuf[lg] + (size_t)cg * mc * CDIM;
            Wq_ = WqkvT + (size_t)lg * 2304 * 256;
        }
        const bf16* WoTl = nullptr; bf16* Hnw = nullptr; const float* bs = nullptr;
        if (gW) {
            int tw = t - 1, lw = tw / c, cw = tw % c;
            WoTl = WoT + (size_t)lw * 256 * 768;
            Hnw = Hbuf[lw + 1] + (size_t)cw * mc * CDIM;
            bs = bsum + lw * CDIM;
        }
        step_kernel<<<gG + gW, 256, 0, stream>>>(Hg, Wq_, QKV, O, WoTl, Hnw, bs, gW, nMblk);
        if (t < TT) attn_all<<<n0 + n1 + n2, 256, 0, stream>>>(QKV, O, n0, n1);
    }

    decode_kernel<<<NPOS / 4, 256, 0, stream>>>(Hbuf[2], Wd, bd, out);
}